// Round 11
// baseline (232.979 us; speedup 1.0000x reference)
//
#include <hip/hip_runtime.h>
#include <hip/hip_bf16.h>
#include <stdint.h>

#define NN 4096
#define DD 512
#define NCLS 512
#define LMARGIN 0.3f
#define NSLOT 128
#define BK 64
#define NTRI 528                  // 32*33/2 triangular 128x128 tiles
#define NPANEL 32

typedef float f32x4 __attribute__((ext_vector_type(4)));
typedef __bf16 bf16x8 __attribute__((ext_vector_type(8)));
typedef unsigned short us8 __attribute__((ext_vector_type(8)));
typedef unsigned int u32;

__device__ __forceinline__ void gld_lds16(const void* g, void* l) {
    __builtin_amdgcn_global_load_lds((const __attribute__((address_space(1))) unsigned int*)g,
                                     (__attribute__((address_space(3))) unsigned int*)l,
                                     16, 0, 0);
}

__device__ __forceinline__ float waveSum(float v) {
#pragma unroll
    for (int s = 32; s > 0; s >>= 1) v += __shfl_down(v, s, 64);
    return v;
}

// ---------- dispatch 1: prep-cast (0..1023) + class sums (1024..1535) + totalSum (1536..1567) ----------
__global__ void k_pre(const float* __restrict__ x, const int* __restrict__ tgt,
                      __hip_bfloat16* __restrict__ xb, float* __restrict__ sq,
                      float* __restrict__ classSum, float* __restrict__ classCnt,
                      float* __restrict__ totalSum) {
    int b = blockIdx.x, tid = threadIdx.x;
    if (b < 1024) {
        int lane = tid & 63, wave = tid >> 6;
        int r = b * 4 + wave;                 // one row per wave
        const f32x4* px = (const f32x4*)(x + (size_t)r * DD) + lane * 2;
        f32x4 v0 = px[0], v1 = px[1];
        float s = v0.x * v0.x + v0.y * v0.y + v0.z * v0.z + v0.w * v0.w +
                  v1.x * v1.x + v1.y * v1.y + v1.z * v1.z + v1.w * v1.w;
        us8 o;
        o[0] = __builtin_bit_cast(unsigned short, __float2bfloat16(v0.x));
        o[1] = __builtin_bit_cast(unsigned short, __float2bfloat16(v0.y));
        o[2] = __builtin_bit_cast(unsigned short, __float2bfloat16(v0.z));
        o[3] = __builtin_bit_cast(unsigned short, __float2bfloat16(v0.w));
        o[4] = __builtin_bit_cast(unsigned short, __float2bfloat16(v1.x));
        o[5] = __builtin_bit_cast(unsigned short, __float2bfloat16(v1.y));
        o[6] = __builtin_bit_cast(unsigned short, __float2bfloat16(v1.z));
        o[7] = __builtin_bit_cast(unsigned short, __float2bfloat16(v1.w));
        *(us8*)((unsigned short*)xb + (size_t)r * DD + lane * 8) = o;
        s = waveSum(s);
        if (lane == 0) sq[r] = s;
    } else if (b < 1536) {
        int c = b - 1024;                     // one class per block
        __shared__ int list[128];
        __shared__ int lcnt;
        if (tid == 0) lcnt = 0;
        __syncthreads();
        for (int i = tid; i < NN; i += 256) {
            if (tgt[i] == c) {
                int p = atomicAdd(&lcnt, 1);  // LDS atomic — cheap
                list[p] = i;
            }
        }
        __syncthreads();
        int n = lcnt;
        float s0 = 0.f, s1 = 0.f;
        for (int p = 0; p < n; ++p) {
            const float* row = x + (size_t)list[p] * DD;
            s0 += row[tid];
            s1 += row[tid + 256];
        }
        classSum[(size_t)c * DD + tid] = s0;
        classSum[(size_t)c * DD + tid + 256] = s1;
        if (tid == 0) classCnt[c] = (float)n;
    } else {
        int q = b - 1536;                     // totalSum: 32 blocks x 128 rows, 32-way atomics
        float s0 = 0.f, s1 = 0.f;
        for (int rr = 0; rr < 128; ++rr) {
            const float* row = x + (size_t)(q * 128 + rr) * DD;
            s0 += row[tid];
            s1 += row[tid + 256];
        }
        atomicAdd(&totalSum[tid], s0);
        atomicAdd(&totalSum[tid + 256], s1);
    }
}

// ---------- dispatch 2: triangular Gram + fused last-arriver rowloss/reduce ----------
__global__ __launch_bounds__(256) void k_gram(const __hip_bfloat16* __restrict__ xb,
                                              const float* __restrict__ sq,
                                              const int* __restrict__ tgt,
                                              const float* __restrict__ x,
                                              const float* __restrict__ classSum,
                                              const float* __restrict__ classCnt,
                                              const float* __restrict__ totalSum,
                                              float* __restrict__ pMax,
                                              float* __restrict__ pMin,
                                              u32* __restrict__ cnt,
                                              float* __restrict__ partial,
                                              float* __restrict__ out) {
    int b = blockIdx.x;
    const int tid = threadIdx.x;
    // triangular decode: (by, bx) with by <= bx over 32x32 tiles of 128
    int by = 0, rem = b;
    while (rem >= 32 - by) { rem -= 32 - by; ++by; }
    int bx = by + rem;

    __shared__ __align__(16) __hip_bfloat16 As[128 * BK];   // 16 KB
    __shared__ __align__(16) __hip_bfloat16 Bs[128 * BK];   // 16 KB
    __shared__ int winMask;
    __shared__ float pr[4][3];
    const int lane = tid & 63, wave = tid >> 6;
    const int wr = wave >> 1, wc = wave & 1;
    const int l15 = lane & 15, quad = lane >> 4;
    const __hip_bfloat16* A0 = xb + (size_t)by * 128 * DD;
    const __hip_bfloat16* B0 = xb + (size_t)bx * 128 * DD;
    const int stRow = tid >> 3;
    const int stCol = ((tid & 7) ^ ((tid >> 3) & 7)) * 8;
    char* AsB = (char*)As;
    char* BsB = (char*)Bs;
    const int ldsOff = wave * 1024;

    f32x4 acc[4][4];
    const f32x4 fz = {0.f, 0.f, 0.f, 0.f};
#pragma unroll
    for (int i = 0; i < 4; ++i)
#pragma unroll
        for (int j = 0; j < 4; ++j) acc[i][j] = fz;

    for (int k0 = 0; k0 < DD; k0 += BK) {
#pragma unroll
        for (int n = 0; n < 4; ++n)
            gld_lds16(A0 + (size_t)(n * 32 + stRow) * DD + k0 + stCol, AsB + n * 4096 + ldsOff);
#pragma unroll
        for (int n = 0; n < 4; ++n)
            gld_lds16(B0 + (size_t)(n * 32 + stRow) * DD + k0 + stCol, BsB + n * 4096 + ldsOff);
        __syncthreads();
#pragma unroll
        for (int kk = 0; kk < 2; ++kk) {
            bf16x8 af[4], bfr[4];
#pragma unroll
            for (int t = 0; t < 4; ++t) {
                int row = wr * 64 + t * 16 + l15;
                af[t] = *(const bf16x8*)(As + row * BK + (((kk * 4 + quad) ^ (l15 & 7)) << 3));
            }
#pragma unroll
            for (int t = 0; t < 4; ++t) {
                int row = wc * 64 + t * 16 + l15;
                bfr[t] = *(const bf16x8*)(Bs + row * BK + (((kk * 4 + quad) ^ (l15 & 7)) << 3));
            }
#pragma unroll
            for (int i = 0; i < 4; ++i)
#pragma unroll
                for (int j = 0; j < 4; ++j)
                    acc[i][j] = __builtin_amdgcn_mfma_f32_16x16x32_bf16(af[i], bfr[j], acc[i][j], 0, 0, 0);
        }
        __syncthreads();
    }

    // epilogue on deferred squared distances (R10 scheme, unchanged)
    const int r0 = by * 128 + wr * 64;
    const int c0 = bx * 128 + wc * 64;
    const int rowSlot = bx * 2 + wc;
    const int colSlot = 64 + by * 2 + wr;
    const float NINF = -__builtin_inff(), PINF = __builtin_inff();
    float sqc[4];
    int tct[4];
#pragma unroll
    for (int j = 0; j < 4; ++j) {
        int c = c0 + j * 16 + l15;
        sqc[j] = sq[c];
        tct[j] = tgt[c];
    }
    float cmax[4], cmin[4];
#pragma unroll
    for (int j = 0; j < 4; ++j) { cmax[j] = NINF; cmin[j] = PINF; }

#pragma unroll
    for (int i = 0; i < 4; ++i) {
#pragma unroll
        for (int rg = 0; rg < 4; ++rg) {
            int r = r0 + i * 16 + quad * 4 + rg;
            float sqr = sq[r];
            int rt = tgt[r];
            float rmax = NINF, rmin = PINF;
#pragma unroll
            for (int j = 0; j < 4; ++j) {
                float t2 = -2.0f * acc[i][j][rg];
                float rv = sqc[j] + t2;
                float cv = sqr + t2;
                if (rt == tct[j]) {
                    rmax = fmaxf(rmax, rv);
                    cmax[j] = fmaxf(cmax[j], cv);
                } else {
                    rmin = fminf(rmin, rv);
                    cmin[j] = fminf(cmin[j], cv);
                }
            }
#pragma unroll
            for (int s = 1; s < 16; s <<= 1) {
                rmax = fmaxf(rmax, __shfl_xor(rmax, s, 64));
                rmin = fminf(rmin, __shfl_xor(rmin, s, 64));
            }
            if (l15 == 0) {
                pMax[(size_t)r * NSLOT + rowSlot] = sqr + rmax;
                pMin[(size_t)r * NSLOT + rowSlot] = sqr + rmin;
            }
        }
    }
#pragma unroll
    for (int j = 0; j < 4; ++j) {
        float vmax = cmax[j], vmin = cmin[j];
        vmax = fmaxf(vmax, __shfl_xor(vmax, 16, 64));
        vmax = fmaxf(vmax, __shfl_xor(vmax, 32, 64));
        vmin = fminf(vmin, __shfl_xor(vmin, 16, 64));
        vmin = fminf(vmin, __shfl_xor(vmin, 32, 64));
        if (quad == 0) {
            int c = c0 + j * 16 + l15;
            pMax[(size_t)c * NSLOT + colSlot] = sqc[j] + vmax;
            pMin[(size_t)c * NSLOT + colSlot] = sqc[j] + vmin;
        }
    }

    // ===== last-arriver finalization (no spinning; R9-verified fence pattern) =====
    if (tid == 0) {
        __threadfence();                               // release this block's slot stores
        int wm = 0;
        if (atomicAdd(&cnt[by], 1u) == NPANEL - 1) wm |= 1;
        if (bx != by && atomicAdd(&cnt[bx], 1u) == NPANEL - 1) wm |= 2;
        winMask = wm;
    }
    __syncthreads();
    int wm = winMask;
    if (wm == 0) return;
    if (tid == 0) __threadfence();                     // acquire remote slot stores
    __syncthreads();

    // preload totalSum fragment (row-invariant)
    const f32x4* tp = (const f32x4*)(totalSum) + lane * 2;
    f32x4 ts0 = tp[0], ts1 = tp[1];

    bool didLast = false;
#pragma unroll 1
    for (int pp = 0; pp < 2; ++pp) {
        if (!(wm & (1 << pp))) continue;
        int p = pp ? bx : by;
        float stl = 0.f, sctl = 0.f, sdcc = 0.f;       // lane-0-valid
#pragma unroll 1
        for (int k = 0; k < 32; ++k) {
            int r = p * 128 + wave * 32 + k;
            int t = tgt[r];
            float cn = classCnt[t];
            float rcp = 1.0f / cn;
            float rcn = 1.0f / ((float)NN - cn);
            const f32x4* px = (const f32x4*)(x + (size_t)r * DD) + lane * 2;
            const f32x4* pc = (const f32x4*)(classSum + (size_t)t * DD) + lane * 2;
            f32x4 xv0 = px[0], xv1 = px[1], cs0 = pc[0], cs1 = pc[1];
            float scp = 0.f, scn = 0.f, scc = 0.f;
#pragma unroll
            for (int e = 0; e < 4; ++e) {
                float ic = cs0[e] * rcp, oc = (ts0[e] - cs0[e]) * rcn;
                float a = ic - xv0[e], b2 = oc - xv0[e], cc2 = ic - oc;
                scp += a * a; scn += b2 * b2; scc += cc2 * cc2;
                float ic1 = cs1[e] * rcp, oc1 = (ts1[e] - cs1[e]) * rcn;
                float a1 = ic1 - xv1[e], b21 = oc1 - xv1[e], cc21 = ic1 - oc1;
                scp += a1 * a1; scn += b21 * b21; scc += cc21 * cc21;
            }
            scp = waveSum(scp);
            scn = waveSum(scn);
            scc = waveSum(scc);
            // slot reduce: lane covers slots {lane, 64+lane} with validity mask
            float a0 = (lane >= 2 * p) ? pMax[(size_t)r * NSLOT + lane] : NINF;
            float a1v = (lane <= 2 * p + 1) ? pMax[(size_t)r * NSLOT + 64 + lane] : NINF;
            float b0 = (lane >= 2 * p) ? pMin[(size_t)r * NSLOT + lane] : PINF;
            float b1v = (lane <= 2 * p + 1) ? pMin[(size_t)r * NSLOT + 64 + lane] : PINF;
            float m2a = fmaxf(a0, a1v);
            float m2n = fminf(b0, b1v);
#pragma unroll
            for (int s = 1; s < 64; s <<= 1) {
                m2a = fmaxf(m2a, __shfl_xor(m2a, s, 64));
                m2n = fminf(m2n, __shfl_xor(m2n, s, 64));
            }
            if (lane == 0) {
                float ap2 = fmaxf(m2a, 1e-12f);
                float an2 = fmaxf(m2n, 1e-12f);
                stl += fmaxf(sqrtf(ap2) - sqrtf(an2) + LMARGIN, 0.f);
                sctl += fmaxf(sqrtf(scp) - sqrtf(scn) + LMARGIN, 0.f);
                sdcc += sqrtf(scc);
            }
        }
        if (lane == 0) { pr[wave][0] = stl; pr[wave][1] = sctl; pr[wave][2] = sdcc; }
        __syncthreads();
        if (tid == 0) {
            partial[p * 3 + 0] = pr[0][0] + pr[1][0] + pr[2][0] + pr[3][0];
            partial[p * 3 + 1] = pr[0][1] + pr[1][1] + pr[2][1] + pr[3][1];
            partial[p * 3 + 2] = pr[0][2] + pr[1][2] + pr[2][2] + pr[3][2];
            __threadfence();
            if (atomicAdd(&cnt[NPANEL], 1u) == NPANEL - 1) winMask = -1;
            else winMask = 0;
        }
        __syncthreads();
        didLast = (winMask == -1);
        __syncthreads();
    }

    if (didLast) {                                     // final reduce over 32 panel partials
        if (tid == 0) __threadfence();                 // acquire remote partials
        __syncthreads();
        if (wave == 0) {
            float s0 = 0.f, s1 = 0.f, s2 = 0.f;
            if (lane < NPANEL) {
                s0 = partial[lane * 3 + 0];
                s1 = partial[lane * 3 + 1];
                s2 = partial[lane * 3 + 2];
            }
#pragma unroll
            for (int s = 1; s < 32; s <<= 1) {
                s0 += __shfl_xor(s0, s, 64);
                s1 += __shfl_xor(s1, s, 64);
                s2 += __shfl_xor(s2, s, 64);
            }
            if (lane == 0) {
                out[0] = s0 * (1.0f / NN);
                out[1] = s1 * (1.0f / NN);
                out[2] = -s2 * (1.0f / NN);
            }
        }
    }
}

extern "C" void kernel_launch(void* const* d_in, const int* in_sizes, int n_in,
                              void* d_out, int out_size, void* d_ws, size_t ws_size,
                              hipStream_t stream) {
    const float* x = (const float*)d_in[0];
    const int* tgt = (const int*)d_in[1];
    float* out = (float*)d_out;
    char* ws = (char*)d_ws;

    size_t o = 0;
    u32* cnt = (u32*)(ws + o);          o += 256;                              // 33 counters
    float* totalSum = (float*)(ws + o); o += (size_t)DD * 4;                   // 2 KB (zeroed)
    __hip_bfloat16* xb = (__hip_bfloat16*)(ws + o); o += (size_t)NN * DD * 2;  // 4 MB
    float* sq = (float*)(ws + o);       o += (size_t)NN * 4;
    float* classSum = (float*)(ws + o); o += (size_t)NCLS * DD * 4;            // 1 MB
    float* classCnt = (float*)(ws + o); o += (size_t)NCLS * 4;
    float* pMax = (float*)(ws + o);     o += (size_t)NN * NSLOT * 4;           // 2 MB
    float* pMin = (float*)(ws + o);     o += (size_t)NN * NSLOT * 4;           // 2 MB
    float* partial = (float*)(ws + o);  o += (size_t)NPANEL * 3 * 4;

    hipMemsetAsync(ws, 0, 256 + DD * 4, stream);       // zero counters + totalSum
    k_pre<<<dim3(1568), dim3(256), 0, stream>>>(x, tgt, xb, sq, classSum, classCnt, totalSum);
    k_gram<<<dim3(NTRI), dim3(256), 0, stream>>>(xb, sq, tgt, x, classSum, classCnt, totalSum,
                                                 pMax, pMin, cnt, partial, out);
}

// Round 12
// 119.412 us; speedup vs baseline: 1.9510x; 1.9510x over previous
//
#include <hip/hip_runtime.h>
#include <hip/hip_bf16.h>
#include <stdint.h>

#define NN 4096
#define DD 512
#define NCLS 512
#define LMARGIN 0.3f
#define NSLOT 256
#define BK 64
#define NPAN 64                   // 64 panels of 64 rows
#define NTRI 2080                 // 64*65/2 triangular 64x64 tiles

typedef float f32x4 __attribute__((ext_vector_type(4)));
typedef __bf16 bf16x8 __attribute__((ext_vector_type(8)));
typedef unsigned short us8 __attribute__((ext_vector_type(8)));

__device__ __forceinline__ void gld_lds16(const void* g, void* l) {
    __builtin_amdgcn_global_load_lds((const __attribute__((address_space(1))) unsigned int*)g,
                                     (__attribute__((address_space(3))) unsigned int*)l,
                                     16, 0, 0);
}

__device__ __forceinline__ float waveSum(float v) {
#pragma unroll
    for (int s = 32; s > 0; s >>= 1) v += __shfl_down(v, s, 64);
    return v;
}

// ---------- fused: per-row bf16 cast + norms (blocks 0..1023), per-class sums (1024..1535) ----------
__global__ void k_prep_csum(const float* __restrict__ x, const int* __restrict__ tgt,
                            __hip_bfloat16* __restrict__ xb, float* __restrict__ sq,
                            float* __restrict__ classSum, float* __restrict__ classCnt) {
    int b = blockIdx.x, tid = threadIdx.x;
    if (b < 1024) {
        int lane = tid & 63, wave = tid >> 6;
        int r = b * 4 + wave;                 // one row per wave
        const f32x4* px = (const f32x4*)(x + (size_t)r * DD) + lane * 2;
        f32x4 v0 = px[0], v1 = px[1];
        float s = v0.x * v0.x + v0.y * v0.y + v0.z * v0.z + v0.w * v0.w +
                  v1.x * v1.x + v1.y * v1.y + v1.z * v1.z + v1.w * v1.w;
        us8 o;
        o[0] = __builtin_bit_cast(unsigned short, __float2bfloat16(v0.x));
        o[1] = __builtin_bit_cast(unsigned short, __float2bfloat16(v0.y));
        o[2] = __builtin_bit_cast(unsigned short, __float2bfloat16(v0.z));
        o[3] = __builtin_bit_cast(unsigned short, __float2bfloat16(v0.w));
        o[4] = __builtin_bit_cast(unsigned short, __float2bfloat16(v1.x));
        o[5] = __builtin_bit_cast(unsigned short, __float2bfloat16(v1.y));
        o[6] = __builtin_bit_cast(unsigned short, __float2bfloat16(v1.z));
        o[7] = __builtin_bit_cast(unsigned short, __float2bfloat16(v1.w));
        *(us8*)((unsigned short*)xb + (size_t)r * DD + lane * 8) = o;
        s = waveSum(s);
        if (lane == 0) sq[r] = s;
    } else {
        int c = b - 1024;                     // one class per block
        __shared__ int list[128];
        __shared__ int lcnt;
        if (tid == 0) lcnt = 0;
        __syncthreads();
        for (int i = tid; i < NN; i += 256) {
            if (tgt[i] == c) {
                int p = atomicAdd(&lcnt, 1);  // LDS atomic — cheap
                list[p] = i;
            }
        }
        __syncthreads();
        int n = lcnt;
        float s0 = 0.f, s1 = 0.f;
        for (int p = 0; p < n; ++p) {
            const float* row = x + (size_t)list[p] * DD;
            s0 += row[tid];
            s1 += row[tid + 256];
        }
        classSum[(size_t)c * DD + tid] = s0;
        classSum[(size_t)c * DD + tid + 256] = s1;
        if (tid == 0) classCnt[c] = (float)n;
    }
}

// ---------- Gram: triangular 64x64 tiles (2080 blocks ~8/CU), BK=64 LDS swizzled ----------
__global__ __launch_bounds__(256) void k_gram(const __hip_bfloat16* __restrict__ xb,
                                              const float* __restrict__ sq,
                                              const int* __restrict__ tgt,
                                              const float* __restrict__ classSum,
                                              float* __restrict__ totalSum,
                                              float* __restrict__ pMax,
                                              float* __restrict__ pMin) {
    int b = blockIdx.x;
    const int tid = threadIdx.x;
    if (b >= NTRI) {                          // totsum tail: 2 blocks x 256 cols
        int d = (b - NTRI) * 256 + tid;
        float s = 0.f;
#pragma unroll 8
        for (int c = 0; c < NCLS; ++c) s += classSum[(size_t)c * DD + d];
        totalSum[d] = s;
        return;
    }
    // triangular decode: (ty, tx) with ty <= tx over 64 panels of 64
    int ty = 0, rem = b;
    while (rem >= NPAN - ty) { rem -= NPAN - ty; ++ty; }
    int tx = ty + rem;

    __shared__ __align__(16) __hip_bfloat16 As[64 * BK];    // 8 KB
    __shared__ __align__(16) __hip_bfloat16 Bs[64 * BK];    // 8 KB
    const int lane = tid & 63, wave = tid >> 6;
    const int wr = wave >> 1, wc = wave & 1;
    const int l15 = lane & 15, quad = lane >> 4;
    const __hip_bfloat16* A0 = xb + (size_t)ty * 64 * DD;
    const __hip_bfloat16* B0 = xb + (size_t)tx * 64 * DD;
    const int stRow = tid >> 3;               // 0..31 per call
    const int stCol = ((tid & 7) ^ ((tid >> 3) & 7)) * 8;   // swizzled global chunk
    char* AsB = (char*)As;
    char* BsB = (char*)Bs;
    const int ldsOff = wave * 1024;

    f32x4 acc[2][2];
    const f32x4 fz = {0.f, 0.f, 0.f, 0.f};
#pragma unroll
    for (int i = 0; i < 2; ++i)
#pragma unroll
        for (int j = 0; j < 2; ++j) acc[i][j] = fz;

    for (int k0 = 0; k0 < DD; k0 += BK) {
#pragma unroll
        for (int n = 0; n < 2; ++n)
            gld_lds16(A0 + (size_t)(n * 32 + stRow) * DD + k0 + stCol, AsB + n * 4096 + ldsOff);
#pragma unroll
        for (int n = 0; n < 2; ++n)
            gld_lds16(B0 + (size_t)(n * 32 + stRow) * DD + k0 + stCol, BsB + n * 4096 + ldsOff);
        __syncthreads();
#pragma unroll
        for (int kk = 0; kk < 2; ++kk) {
            bf16x8 af[2], bfr[2];
#pragma unroll
            for (int t = 0; t < 2; ++t) {
                int row = wr * 32 + t * 16 + l15;
                af[t] = *(const bf16x8*)(As + row * BK + (((kk * 4 + quad) ^ (l15 & 7)) << 3));
            }
#pragma unroll
            for (int t = 0; t < 2; ++t) {
                int row = wc * 32 + t * 16 + l15;
                bfr[t] = *(const bf16x8*)(Bs + row * BK + (((kk * 4 + quad) ^ (l15 & 7)) << 3));
            }
#pragma unroll
            for (int i = 0; i < 2; ++i)
#pragma unroll
                for (int j = 0; j < 2; ++j)
                    acc[i][j] = __builtin_amdgcn_mfma_f32_16x16x32_bf16(af[i], bfr[j], acc[i][j], 0, 0, 0);
        }
        __syncthreads();
    }

    // epilogue on deferred squared distances (R10 algebra):
    //   row side: reduce (sqc - 2g) over cols, add sqr at store -> slot tx*2+wc
    //   col side: reduce (sqr - 2g) over rows, add sqc at store -> slot 128+ty*2+wr
    const int r0 = ty * 64 + wr * 32;
    const int c0 = tx * 64 + wc * 32;
    const int rowSlot = tx * 2 + wc;
    const int colSlot = 128 + ty * 2 + wr;
    const float NINF = -__builtin_inff(), PINF = __builtin_inff();
    float sqc[2];
    int tct[2];
#pragma unroll
    for (int j = 0; j < 2; ++j) {
        int c = c0 + j * 16 + l15;
        sqc[j] = sq[c];
        tct[j] = tgt[c];
    }
    float cmax[2], cmin[2];
#pragma unroll
    for (int j = 0; j < 2; ++j) { cmax[j] = NINF; cmin[j] = PINF; }

#pragma unroll
    for (int i = 0; i < 2; ++i) {
#pragma unroll
        for (int rg = 0; rg < 4; ++rg) {
            int r = r0 + i * 16 + quad * 4 + rg;
            float sqr = sq[r];
            int rt = tgt[r];
            float rmax = NINF, rmin = PINF;
#pragma unroll
            for (int j = 0; j < 2; ++j) {
                float t2 = -2.0f * acc[i][j][rg];
                float rv = sqc[j] + t2;
                float cv = sqr + t2;
                if (rt == tct[j]) {
                    rmax = fmaxf(rmax, rv);
                    cmax[j] = fmaxf(cmax[j], cv);
                } else {
                    rmin = fminf(rmin, rv);
                    cmin[j] = fminf(cmin[j], cv);
                }
            }
#pragma unroll
            for (int s = 1; s < 16; s <<= 1) {   // reduce over 16 l15 lanes
                rmax = fmaxf(rmax, __shfl_xor(rmax, s, 64));
                rmin = fminf(rmin, __shfl_xor(rmin, s, 64));
            }
            if (l15 == 0) {
                pMax[(size_t)r * NSLOT + rowSlot] = sqr + rmax;
                pMin[(size_t)r * NSLOT + rowSlot] = sqr + rmin;
            }
        }
    }
#pragma unroll
    for (int j = 0; j < 2; ++j) {               // col stats: reduce across quads
        float vmax = cmax[j], vmin = cmin[j];
        vmax = fmaxf(vmax, __shfl_xor(vmax, 16, 64));
        vmax = fmaxf(vmax, __shfl_xor(vmax, 32, 64));
        vmin = fminf(vmin, __shfl_xor(vmin, 16, 64));
        vmin = fminf(vmin, __shfl_xor(vmin, 32, 64));
        if (quad == 0) {
            int c = c0 + j * 16 + l15;
            pMax[(size_t)c * NSLOT + colSlot] = sqc[j] + vmax;
            pMin[(size_t)c * NSLOT + colSlot] = sqc[j] + vmin;
        }
    }
}

// ---------- per-row centroid losses + triplet terms + masked 256-slot reduce ----------
__global__ void k_rowloss(const float* __restrict__ x, const int* __restrict__ tgt,
                          const float* __restrict__ classSum, const float* __restrict__ classCnt,
                          const float* __restrict__ totalSum, const float* __restrict__ pMax,
                          const float* __restrict__ pMin,
                          float* __restrict__ tlArr, float* __restrict__ ctlArr,
                          float* __restrict__ dccArr) {
    int i = blockIdx.x, tid = threadIdx.x;  // 256 threads
    int lane = tid & 63;
    int t = tgt[i];
    int p = i >> 6;                          // panel of this row
    const float NINF = -__builtin_inff(), PINF = __builtin_inff();
    float cnt = classCnt[t];
    float rcp = 1.0f / cnt;
    float rcn = 1.0f / ((float)NN - cnt);
    float scp = 0.f, scn = 0.f, scc = 0.f;
#pragma unroll
    for (int jj = 0; jj < 2; ++jj) {
        int d = tid + jj * 256;
        float xv = x[(size_t)i * DD + d];
        float cs = classSum[t * DD + d];
        float ts = totalSum[d];
        float ic = cs * rcp;
        float oc = (ts - cs) * rcn;
        float a = ic - xv, b2 = oc - xv, c = ic - oc;
        scp += a * a;
        scn += b2 * b2;
        scc += c * c;
    }
    scp = waveSum(scp);
    scn = waveSum(scn);
    scc = waveSum(scc);
    __shared__ float red[4][3];
    __shared__ float mred[4];   // [0,1] = max (row,col sides), [2,3] = min
    int w = tid >> 6;
    if ((tid & 63) == 0) { red[w][0] = scp; red[w][1] = scn; red[w][2] = scc; }
    // slot validity: row-slots s in [0,128): valid iff (s>>1) >= p;
    //                col-slots s in [128,256): valid iff ((s-128)>>1) <= p
    if (w == 0) {               // max over row-side slots
        int s0 = lane, s1 = lane + 64;
        float m = ((s0 >> 1) >= p) ? pMax[(size_t)i * NSLOT + s0] : NINF;
        if ((s1 >> 1) >= p) m = fmaxf(m, pMax[(size_t)i * NSLOT + s1]);
#pragma unroll
        for (int s = 32; s > 0; s >>= 1) m = fmaxf(m, __shfl_down(m, s, 64));
        if (lane == 0) mred[0] = m;
    } else if (w == 1) {        // max over col-side slots
        int s0 = lane, s1 = lane + 64;
        float m = ((s0 >> 1) <= p) ? pMax[(size_t)i * NSLOT + 128 + s0] : NINF;
        if ((s1 >> 1) <= p) m = fmaxf(m, pMax[(size_t)i * NSLOT + 128 + s1]);
#pragma unroll
        for (int s = 32; s > 0; s >>= 1) m = fmaxf(m, __shfl_down(m, s, 64));
        if (lane == 0) mred[1] = m;
    } else if (w == 2) {        // min over row-side slots
        int s0 = lane, s1 = lane + 64;
        float m = ((s0 >> 1) >= p) ? pMin[(size_t)i * NSLOT + s0] : PINF;
        if ((s1 >> 1) >= p) m = fminf(m, pMin[(size_t)i * NSLOT + s1]);
#pragma unroll
        for (int s = 32; s > 0; s >>= 1) m = fminf(m, __shfl_down(m, s, 64));
        if (lane == 0) mred[2] = m;
    } else {                    // min over col-side slots
        int s0 = lane, s1 = lane + 64;
        float m = ((s0 >> 1) <= p) ? pMin[(size_t)i * NSLOT + 128 + s0] : PINF;
        if ((s1 >> 1) <= p) m = fminf(m, pMin[(size_t)i * NSLOT + 128 + s1]);
#pragma unroll
        for (int s = 32; s > 0; s >>= 1) m = fminf(m, __shfl_down(m, s, 64));
        if (lane == 0) mred[3] = m;
    }
    __syncthreads();
    if (tid == 0) {
        float pp = red[0][0] + red[1][0] + red[2][0] + red[3][0];
        float n2 = red[0][1] + red[1][1] + red[2][1] + red[3][1];
        float cc = red[0][2] + red[1][2] + red[2][2] + red[3][2];
        float dcp = sqrtf(pp), dcn = sqrtf(n2), dcc = sqrtf(cc);
        float ap2 = fmaxf(fmaxf(mred[0], mred[1]), 1e-12f);
        float an2 = fmaxf(fminf(mred[2], mred[3]), 1e-12f);
        tlArr[i] = fmaxf(sqrtf(ap2) - sqrtf(an2) + LMARGIN, 0.f);
        ctlArr[i] = fmaxf(dcp - dcn + LMARGIN, 0.f);
        dccArr[i] = dcc;
    }
}

// ---------- single-block final reduction over 3 x NN values ----------
__global__ __launch_bounds__(1024) void k_reduce(const float* __restrict__ tlArr,
                                                 const float* __restrict__ ctlArr,
                                                 const float* __restrict__ dccArr,
                                                 float* __restrict__ out) {
    int tid = threadIdx.x;  // 1024 threads
    float s0 = 0.f, s1 = 0.f, s2 = 0.f;
#pragma unroll
    for (int jj = 0; jj < NN / 1024; ++jj) {
        int i = tid + jj * 1024;
        s0 += tlArr[i];
        s1 += ctlArr[i];
        s2 += dccArr[i];
    }
    s0 = waveSum(s0);
    s1 = waveSum(s1);
    s2 = waveSum(s2);
    __shared__ float red[16][3];
    int w = tid >> 6;
    if ((tid & 63) == 0) { red[w][0] = s0; red[w][1] = s1; red[w][2] = s2; }
    __syncthreads();
    if (tid == 0) {
        float a = 0.f, b = 0.f, c = 0.f;
#pragma unroll
        for (int k = 0; k < 16; ++k) { a += red[k][0]; b += red[k][1]; c += red[k][2]; }
        out[0] = a * (1.0f / NN);
        out[1] = b * (1.0f / NN);
        out[2] = -c * (1.0f / NN);
    }
}

extern "C" void kernel_launch(void* const* d_in, const int* in_sizes, int n_in,
                              void* d_out, int out_size, void* d_ws, size_t ws_size,
                              hipStream_t stream) {
    const float* x = (const float*)d_in[0];
    const int* tgt = (const int*)d_in[1];
    float* out = (float*)d_out;
    char* ws = (char*)d_ws;

    size_t o = 0;
    __hip_bfloat16* xb = (__hip_bfloat16*)(ws + o); o += (size_t)NN * DD * 2;  // 4 MB
    float* sq = (float*)(ws + o);       o += (size_t)NN * 4;
    float* classSum = (float*)(ws + o); o += (size_t)NCLS * DD * 4;            // 1 MB
    float* classCnt = (float*)(ws + o); o += (size_t)NCLS * 4;
    float* totalSum = (float*)(ws + o); o += (size_t)DD * 4;
    float* pMax = (float*)(ws + o);     o += (size_t)NN * NSLOT * 4;           // 4 MB
    float* pMin = (float*)(ws + o);     o += (size_t)NN * NSLOT * 4;           // 4 MB
    float* tlArr = (float*)(ws + o);    o += (size_t)NN * 4;
    float* ctlArr = (float*)(ws + o);   o += (size_t)NN * 4;
    float* dccArr = (float*)(ws + o);   o += (size_t)NN * 4;

    k_prep_csum<<<dim3(1536), dim3(256), 0, stream>>>(x, tgt, xb, sq, classSum, classCnt);
    k_gram<<<dim3(NTRI + 2), dim3(256), 0, stream>>>(xb, sq, tgt, classSum, totalSum, pMax, pMin);
    k_rowloss<<<dim3(NN), dim3(256), 0, stream>>>(x, tgt, classSum, classCnt, totalSum,
                                                  pMax, pMin, tlArr, ctlArr, dccArr);
    k_reduce<<<dim3(1), dim3(1024), 0, stream>>>(tlArr, ctlArr, dccArr, out);
}

// Round 13
// 118.836 us; speedup vs baseline: 1.9605x; 1.0049x over previous
//
#include <hip/hip_runtime.h>
#include <hip/hip_bf16.h>
#include <stdint.h>

#define NN 4096
#define DD 512
#define NCLS 512
#define LMARGIN 0.3f
#define NSLOT 128
#define BK 64
#define NTRI 528                  // 32*33/2 triangular 128x128 tiles

typedef float f32x4 __attribute__((ext_vector_type(4)));
typedef __bf16 bf16x8 __attribute__((ext_vector_type(8)));
typedef unsigned short us8 __attribute__((ext_vector_type(8)));

__device__ __forceinline__ void gld_lds16(const void* g, void* l) {
    __builtin_amdgcn_global_load_lds((const __attribute__((address_space(1))) unsigned int*)g,
                                     (__attribute__((address_space(3))) unsigned int*)l,
                                     16, 0, 0);
}

__device__ __forceinline__ float waveSum(float v) {
#pragma unroll
    for (int s = 32; s > 0; s >>= 1) v += __shfl_down(v, s, 64);
    return v;
}

// ---------- fused: per-row bf16 cast + norms (blocks 0..1023), per-class sums (1024..1535) ----------
__global__ void k_prep_csum(const float* __restrict__ x, const int* __restrict__ tgt,
                            __hip_bfloat16* __restrict__ xb, float* __restrict__ sq,
                            float* __restrict__ classSum, float* __restrict__ classCnt) {
    int b = blockIdx.x, tid = threadIdx.x;
    if (b < 1024) {
        int lane = tid & 63, wave = tid >> 6;
        int r = b * 4 + wave;                 // one row per wave
        const f32x4* px = (const f32x4*)(x + (size_t)r * DD) + lane * 2;
        f32x4 v0 = px[0], v1 = px[1];
        float s = v0.x * v0.x + v0.y * v0.y + v0.z * v0.z + v0.w * v0.w +
                  v1.x * v1.x + v1.y * v1.y + v1.z * v1.z + v1.w * v1.w;
        us8 o;
        o[0] = __builtin_bit_cast(unsigned short, __float2bfloat16(v0.x));
        o[1] = __builtin_bit_cast(unsigned short, __float2bfloat16(v0.y));
        o[2] = __builtin_bit_cast(unsigned short, __float2bfloat16(v0.z));
        o[3] = __builtin_bit_cast(unsigned short, __float2bfloat16(v0.w));
        o[4] = __builtin_bit_cast(unsigned short, __float2bfloat16(v1.x));
        o[5] = __builtin_bit_cast(unsigned short, __float2bfloat16(v1.y));
        o[6] = __builtin_bit_cast(unsigned short, __float2bfloat16(v1.z));
        o[7] = __builtin_bit_cast(unsigned short, __float2bfloat16(v1.w));
        *(us8*)((unsigned short*)xb + (size_t)r * DD + lane * 8) = o;
        s = waveSum(s);
        if (lane == 0) sq[r] = s;
    } else {
        int c = b - 1024;                     // one class per block
        __shared__ int list[128];
        __shared__ int lcnt;
        if (tid == 0) lcnt = 0;
        __syncthreads();
        for (int i = tid; i < NN; i += 256) {
            if (tgt[i] == c) {
                int p = atomicAdd(&lcnt, 1);  // LDS atomic — cheap
                list[p] = i;
            }
        }
        __syncthreads();
        int n = lcnt;
        float s0 = 0.f, s1 = 0.f;
        for (int p = 0; p < n; ++p) {
            const float* row = x + (size_t)list[p] * DD;
            s0 += row[tid];
            s1 += row[tid + 256];
        }
        classSum[(size_t)c * DD + tid] = s0;
        classSum[(size_t)c * DD + tid + 256] = s1;
        if (tid == 0) classCnt[c] = (float)n;
    }
}

// ---------- Gram: triangular, 128x128 tile, BK=64 double-buffered LDS, swizzled ----------
__global__ __launch_bounds__(256) void k_gram(const __hip_bfloat16* __restrict__ xb,
                                              const float* __restrict__ sq,
                                              const int* __restrict__ tgt,
                                              const float* __restrict__ classSum,
                                              float* __restrict__ totalSum,
                                              float* __restrict__ pMax,
                                              float* __restrict__ pMin) {
    int b = blockIdx.x;
    const int tid = threadIdx.x;
    if (b >= NTRI) {                          // totsum tail: 2 blocks x 256 cols
        int d = (b - NTRI) * 256 + tid;
        float s = 0.f;
#pragma unroll 8
        for (int c = 0; c < NCLS; ++c) s += classSum[(size_t)c * DD + d];
        totalSum[d] = s;
        return;
    }
    // triangular decode: (by, bx) with by <= bx over 32x32 tiles of 128
    int by = 0, rem = b;
    while (rem >= 32 - by) { rem -= 32 - by; ++by; }
    int bx = by + rem;

    __shared__ __align__(16) __hip_bfloat16 As[2][128 * BK];   // 2 x 16 KB
    __shared__ __align__(16) __hip_bfloat16 Bs[2][128 * BK];   // 2 x 16 KB
    const int lane = tid & 63, wave = tid >> 6;
    const int wr = wave >> 1, wc = wave & 1;
    const int l15 = lane & 15, quad = lane >> 4;
    const __hip_bfloat16* A0 = xb + (size_t)by * 128 * DD;
    const __hip_bfloat16* B0 = xb + (size_t)bx * 128 * DD;
    const int stRow = tid >> 3;
    const int stCol = ((tid & 7) ^ ((tid >> 3) & 7)) * 8;
    const int ldsOff = wave * 1024;

    f32x4 acc[4][4];
    const f32x4 fz = {0.f, 0.f, 0.f, 0.f};
#pragma unroll
    for (int i = 0; i < 4; ++i)
#pragma unroll
        for (int j = 0; j < 4; ++j) acc[i][j] = fz;

    // stage K-chunk k0 into buffer `buf`
#define STAGE(k0, buf)                                                                        \
    do {                                                                                      \
        char* AsB = (char*)As[buf];                                                           \
        char* BsB = (char*)Bs[buf];                                                           \
        _Pragma("unroll")                                                                     \
        for (int n = 0; n < 4; ++n)                                                           \
            gld_lds16(A0 + (size_t)(n * 32 + stRow) * DD + (k0) + stCol, AsB + n * 4096 + ldsOff); \
        _Pragma("unroll")                                                                     \
        for (int n = 0; n < 4; ++n)                                                           \
            gld_lds16(B0 + (size_t)(n * 32 + stRow) * DD + (k0) + stCol, BsB + n * 4096 + ldsOff); \
    } while (0)

    STAGE(0, 0);
    __syncthreads();                           // buf 0 ready
    int buf = 0;
    for (int k0 = 0; k0 < DD; k0 += BK, buf ^= 1) {
        if (k0 + BK < DD) STAGE(k0 + BK, buf ^ 1);   // prefetch next chunk first
        const __hip_bfloat16* Asb = As[buf];
        const __hip_bfloat16* Bsb = Bs[buf];
#pragma unroll
        for (int kk = 0; kk < 2; ++kk) {
            bf16x8 af[4], bfr[4];
#pragma unroll
            for (int t = 0; t < 4; ++t) {
                int row = wr * 64 + t * 16 + l15;
                af[t] = *(const bf16x8*)(Asb + row * BK + (((kk * 4 + quad) ^ (l15 & 7)) << 3));
            }
#pragma unroll
            for (int t = 0; t < 4; ++t) {
                int row = wc * 64 + t * 16 + l15;
                bfr[t] = *(const bf16x8*)(Bsb + row * BK + (((kk * 4 + quad) ^ (l15 & 7)) << 3));
            }
#pragma unroll
            for (int i = 0; i < 4; ++i)
#pragma unroll
                for (int j = 0; j < 4; ++j)
                    acc[i][j] = __builtin_amdgcn_mfma_f32_16x16x32_bf16(af[i], bfr[j], acc[i][j], 0, 0, 0);
        }
        __syncthreads();                       // drains prefetch (after compute) + guards reuse
    }
#undef STAGE

    // epilogue on deferred squared distances (R10 scheme, unchanged)
    const int r0 = by * 128 + wr * 64;
    const int c0 = bx * 128 + wc * 64;
    const int rowSlot = bx * 2 + wc;
    const int colSlot = 64 + by * 2 + wr;
    const float NINF = -__builtin_inff(), PINF = __builtin_inff();
    float sqc[4];
    int tct[4];
#pragma unroll
    for (int j = 0; j < 4; ++j) {
        int c = c0 + j * 16 + l15;
        sqc[j] = sq[c];
        tct[j] = tgt[c];
    }
    float cmax[4], cmin[4];
#pragma unroll
    for (int j = 0; j < 4; ++j) { cmax[j] = NINF; cmin[j] = PINF; }

#pragma unroll
    for (int i = 0; i < 4; ++i) {
#pragma unroll
        for (int rg = 0; rg < 4; ++rg) {
            int r = r0 + i * 16 + quad * 4 + rg;
            float sqr = sq[r];
            int rt = tgt[r];
            float rmax = NINF, rmin = PINF;
#pragma unroll
            for (int j = 0; j < 4; ++j) {
                float t2 = -2.0f * acc[i][j][rg];
                float rv = sqc[j] + t2;
                float cv = sqr + t2;
                if (rt == tct[j]) {
                    rmax = fmaxf(rmax, rv);
                    cmax[j] = fmaxf(cmax[j], cv);
                } else {
                    rmin = fminf(rmin, rv);
                    cmin[j] = fminf(cmin[j], cv);
                }
            }
#pragma unroll
            for (int s = 1; s < 16; s <<= 1) {
                rmax = fmaxf(rmax, __shfl_xor(rmax, s, 64));
                rmin = fminf(rmin, __shfl_xor(rmin, s, 64));
            }
            if (l15 == 0) {
                pMax[(size_t)r * NSLOT + rowSlot] = sqr + rmax;
                pMin[(size_t)r * NSLOT + rowSlot] = sqr + rmin;
            }
        }
    }
#pragma unroll
    for (int j = 0; j < 4; ++j) {
        float vmax = cmax[j], vmin = cmin[j];
        vmax = fmaxf(vmax, __shfl_xor(vmax, 16, 64));
        vmax = fmaxf(vmax, __shfl_xor(vmax, 32, 64));
        vmin = fminf(vmin, __shfl_xor(vmin, 16, 64));
        vmin = fminf(vmin, __shfl_xor(vmin, 32, 64));
        if (quad == 0) {
            int c = c0 + j * 16 + l15;
            pMax[(size_t)c * NSLOT + colSlot] = sqc[j] + vmax;
            pMin[(size_t)c * NSLOT + colSlot] = sqc[j] + vmin;
        }
    }
}

// ---------- per-row centroid losses + triplet terms + masked slot reduce ----------
__global__ void k_rowloss(const float* __restrict__ x, const int* __restrict__ tgt,
                          const float* __restrict__ classSum, const float* __restrict__ classCnt,
                          const float* __restrict__ totalSum, const float* __restrict__ pMax,
                          const float* __restrict__ pMin,
                          float* __restrict__ tlArr, float* __restrict__ ctlArr,
                          float* __restrict__ dccArr) {
    int i = blockIdx.x, tid = threadIdx.x;  // 256 threads
    int lane = tid & 63;
    int t = tgt[i];
    int tile2 = (i >> 7) * 2;
    float cnt = classCnt[t];
    float rcp = 1.0f / cnt;
    float rcn = 1.0f / ((float)NN - cnt);
    float scp = 0.f, scn = 0.f, scc = 0.f;
#pragma unroll
    for (int jj = 0; jj < 2; ++jj) {
        int d = tid + jj * 256;
        float xv = x[(size_t)i * DD + d];
        float cs = classSum[t * DD + d];
        float ts = totalSum[d];
        float ic = cs * rcp;
        float oc = (ts - cs) * rcn;
        float a = ic - xv, b2 = oc - xv, c = ic - oc;
        scp += a * a;
        scn += b2 * b2;
        scc += c * c;
    }
    scp = waveSum(scp);
    scn = waveSum(scn);
    scc = waveSum(scc);
    __shared__ float red[4][3];
    __shared__ float mred[4];   // [0,1] = max halves, [2,3] = min halves
    int w = tid >> 6;
    if ((tid & 63) == 0) { red[w][0] = scp; red[w][1] = scn; red[w][2] = scc; }
    if (w < 2) {
        int slot = w * 64 + lane;
        bool valid = (slot < 64) ? (slot >= tile2) : (slot - 64 <= tile2 + 1);
        float m = valid ? pMax[(size_t)i * NSLOT + slot] : -__builtin_inff();
#pragma unroll
        for (int s = 32; s > 0; s >>= 1) m = fmaxf(m, __shfl_down(m, s, 64));
        if (lane == 0) mred[w] = m;
    } else {
        int slot = (w - 2) * 64 + lane;
        bool valid = (slot < 64) ? (slot >= tile2) : (slot - 64 <= tile2 + 1);
        float m = valid ? pMin[(size_t)i * NSLOT + slot] : __builtin_inff();
#pragma unroll
        for (int s = 32; s > 0; s >>= 1) m = fminf(m, __shfl_down(m, s, 64));
        if (lane == 0) mred[w] = m;
    }
    __syncthreads();
    if (tid == 0) {
        float p = red[0][0] + red[1][0] + red[2][0] + red[3][0];
        float n2 = red[0][1] + red[1][1] + red[2][1] + red[3][1];
        float cc = red[0][2] + red[1][2] + red[2][2] + red[3][2];
        float dcp = sqrtf(p), dcn = sqrtf(n2), dcc = sqrtf(cc);
        float ap2 = fmaxf(fmaxf(mred[0], mred[1]), 1e-12f);
        float an2 = fmaxf(fminf(mred[2], mred[3]), 1e-12f);
        tlArr[i] = fmaxf(sqrtf(ap2) - sqrtf(an2) + LMARGIN, 0.f);
        ctlArr[i] = fmaxf(dcp - dcn + LMARGIN, 0.f);
        dccArr[i] = dcc;
    }
}

// ---------- single-block final reduction over 3 x NN values ----------
__global__ __launch_bounds__(1024) void k_reduce(const float* __restrict__ tlArr,
                                                 const float* __restrict__ ctlArr,
                                                 const float* __restrict__ dccArr,
                                                 float* __restrict__ out) {
    int tid = threadIdx.x;  // 1024 threads
    float s0 = 0.f, s1 = 0.f, s2 = 0.f;
#pragma unroll
    for (int jj = 0; jj < NN / 1024; ++jj) {
        int i = tid + jj * 1024;
        s0 += tlArr[i];
        s1 += ctlArr[i];
        s2 += dccArr[i];
    }
    s0 = waveSum(s0);
    s1 = waveSum(s1);
    s2 = waveSum(s2);
    __shared__ float red[16][3];
    int w = tid >> 6;
    if ((tid & 63) == 0) { red[w][0] = s0; red[w][1] = s1; red[w][2] = s2; }
    __syncthreads();
    if (tid == 0) {
        float a = 0.f, b = 0.f, c = 0.f;
#pragma unroll
        for (int k = 0; k < 16; ++k) { a += red[k][0]; b += red[k][1]; c += red[k][2]; }
        out[0] = a * (1.0f / NN);
        out[1] = b * (1.0f / NN);
        out[2] = -c * (1.0f / NN);
    }
}

extern "C" void kernel_launch(void* const* d_in, const int* in_sizes, int n_in,
                              void* d_out, int out_size, void* d_ws, size_t ws_size,
                              hipStream_t stream) {
    const float* x = (const float*)d_in[0];
    const int* tgt = (const int*)d_in[1];
    float* out = (float*)d_out;
    char* ws = (char*)d_ws;

    size_t o = 0;
    __hip_bfloat16* xb = (__hip_bfloat16*)(ws + o); o += (size_t)NN * DD * 2;  // 4 MB
    float* sq = (float*)(ws + o);       o += (size_t)NN * 4;
    float* classSum = (float*)(ws + o); o += (size_t)NCLS * DD * 4;            // 1 MB
    float* classCnt = (float*)(ws + o); o += (size_t)NCLS * 4;
    float* totalSum = (float*)(ws + o); o += (size_t)DD * 4;
    float* pMax = (float*)(ws + o);     o += (size_t)NN * NSLOT * 4;           // 2 MB
    float* pMin = (float*)(ws + o);     o += (size_t)NN * NSLOT * 4;           // 2 MB
    float* tlArr = (float*)(ws + o);    o += (size_t)NN * 4;
    float* ctlArr = (float*)(ws + o);   o += (size_t)NN * 4;
    float* dccArr = (float*)(ws + o);   o += (size_t)NN * 4;

    k_prep_csum<<<dim3(1536), dim3(256), 0, stream>>>(x, tgt, xb, sq, classSum, classCnt);
    k_gram<<<dim3(NTRI + 2), dim3(256), 0, stream>>>(xb, sq, tgt, classSum, totalSum, pMax, pMin);
    k_rowloss<<<dim3(NN), dim3(256), 0, stream>>>(x, tgt, classSum, classCnt, totalSum,
                                                  pMax, pMin, tlArr, ctlArr, dccArr);
    k_reduce<<<dim3(1), dim3(1024), 0, stream>>>(tlArr, ctlArr, dccArr, out);
}